// Round 5
// baseline (1893.864 us; speedup 1.0000x reference)
//
#include <hip/hip_runtime.h>
#include <hip/hip_cooperative_groups.h>
#include <math.h>

namespace cg = cooperative_groups;

#define B_ 2
#define NA_ 4096
#define NR_ 512
#define D_ 128
#define H_ 8
#define DH_ 16
#define NLOCAL_ 5
#define NIPA_ 4
#define NITER_ 3

__device__ __forceinline__ float gelu_tanh(float x) {
  float x3 = x * x * x;
  return 0.5f * x * (1.0f + tanhf(0.7978845608028654f * (x + 0.044715f * x3)));
}
__device__ __forceinline__ unsigned int pack_bf(float lo, float hi) {
  unsigned int a = __float_as_uint(lo);
  unsigned int b = __float_as_uint(hi);
  a = (a + 0x7fffu + ((a >> 16) & 1u)) >> 16;
  b = (b + 0x7fffu + ((b >> 16) & 1u)) & 0xffff0000u;
  return b | a;
}
__device__ __forceinline__ float bf_lo(unsigned int u) { return __uint_as_float(u << 16); }
__device__ __forceinline__ float bf_hi(unsigned int u) { return __uint_as_float(u & 0xffff0000u); }

struct Args {
  const float* coords; const int* atype; const int* rtype; const float* res_mask;
  const int* res_map; const float* rots_bad; const float* trans_bad;
  const float* atom_emb; const float* res_emb; const float* coord_W; const float* coord_b;
  const float* local_W; const float* local_b; const float* pair_W; const float* pair_b;
  const float* Wq; const float* Wk; const float* Wv; const float* Wb;
  const float* Wo; const float* bo; const float* head_W; const float* head_b;
  float* feats0;  // ALIASED with ob (disjoint lifetimes: feats0 dead after stage A)
  float* featsL; float* featsW; float* qb; float* ob;
  float* weff; float* beff; float* curR; float* curT; float* out;
  unsigned int* kb; unsigned int* vb;
  unsigned int* lwb; unsigned int* qkvb; unsigned int* wob;
};

struct AttnSM {
  unsigned int ks[NR_][9];
  unsigned int vs[NR_][9];
  float ts[NR_][3];
  float ms[NR_];
  float ps[4][NR_];
};
union SMU {
  AttnSM a;
  float xs[4][D_];
};

// helper: one wave computes q,k,v row projections for layer ln from xs into qb/kb/vb
__device__ __forceinline__ void qkv_from_xs(const Args& A, const float* xs, int row, int cp,
                                            int ln) {
#pragma unroll
  for (int m = 0; m < 3; m++) {
    const unsigned int* Wm = A.qkvb + (ln * 3 + m) * 8192;
    float b0 = 0.f, b1 = 0.f;
#pragma unroll 16
    for (int k = 0; k < 128; k++) {
      float x = xs[k];
      unsigned int pk = Wm[k * 64 + cp];
      b0 += x * bf_lo(pk); b1 += x * bf_hi(pk);
    }
    if (m == 0)
      *(float2*)(A.qb + (size_t)row * D_ + 2 * cp) = make_float2(b0, b1);
    else {
      int h = cp >> 3, u = cp & 7;
      unsigned int pk = pack_bf(b0, b1);
      if (m == 1) A.kb[((h << 10) + row) * 8 + u] = pk;
      else A.vb[((h << 10) + row) * 8 + u] = pk;
    }
  }
}

__global__ __launch_bounds__(256) void mega(Args A) {
  cg::grid_group grid = cg::this_grid();
  __shared__ SMU sm;
  const int tid = threadIdx.x;
  const int bid = blockIdx.x;
  const int gtid = (bid << 8) + tid;  // 0..65535

  // ================= stage P: weight pack + weff + frame init + pooling =================
  for (int t = gtid; t < 172032; t += 65536) {
    if (t < 40960) {
      int cp = t & 63, k = (t >> 6) & 127, l = t >> 13;
      const float* s = A.local_W + ((size_t)(l * 128 + k) * 128 + 2 * cp);
      A.lwb[t] = pack_bf(s[0], s[1]);
    } else if (t < 139264) {
      int t2 = t - 40960;
      int l = t2 / 24576, rem = t2 % 24576;
      int m = rem >> 13, k = (rem >> 6) & 127, cp = rem & 63;
      const float* base = (m == 0) ? A.Wq : ((m == 1) ? A.Wk : A.Wv);
      const float* s = base + ((size_t)l * 16384 + k * 128 + 2 * cp);
      A.qkvb[t2] = pack_bf(s[0], s[1]);
    } else {
      int t3 = t - 139264;
      int l = t3 >> 13, k = (t3 >> 6) & 127, cp = t3 & 63;
      const float* s = A.Wo + ((size_t)l * 16384 + k * 128 + 2 * cp);
      A.wob[t3] = pack_bf(s[0], s[1]);
    }
  }
  if (gtid < 160) {
    int l = gtid / 40, rest = gtid % 40;
    int c = rest / 8, h = rest & 7;
    const float* row = (c < 4) ? (A.pair_W + c * D_) : A.pair_b;
    float acc = 0.f;
    for (int d = 0; d < D_; d++) acc += row[d] * A.Wb[l * D_ * H_ + d * H_ + h];
    if (c < 4) A.weff[l * 32 + c * 8 + h] = acc;
    else A.beff[l * 8 + h] = acc;
  }
  if (gtid < 9216) A.curR[gtid] = A.rots_bad[gtid];
  else if (gtid < 12288) A.curT[gtid - 9216] = A.trans_bad[gtid - 9216];
  // pooling: 1024 rows, 2 rows per 256-thread pass, 2 passes
  for (int rp = 0; rp < 2; rp++) {
    int row = (bid << 2) + (rp << 1) + (tid >> 7);
    int d = tid & 127;
    int b = row >> 9, rr = row & (NR_ - 1);
    const int* rm = A.res_map + b * NA_;
    int lo = 0, hi = NA_;
    while (lo < hi) { int mid = (lo + hi) >> 1; if (rm[mid] < rr) lo = mid + 1; else hi = mid; }
    int start = lo;
    hi = NA_;
    while (lo < hi) { int mid = (lo + hi) >> 1; if (rm[mid] < rr + 1) lo = mid + 1; else hi = mid; }
    int end = lo;
    float w0 = A.coord_W[d], w1 = A.coord_W[D_ + d], w2 = A.coord_W[2 * D_ + d];
    float cb = A.coord_b[d];
    float s = 0.f;
    for (int a = start; a < end; a++) {
      int ga = b * NA_ + a;
      int at = A.atype[ga], rt = A.rtype[ga];
      s += A.atom_emb[at * D_ + d] + A.res_emb[rt * D_ + d] + A.coords[ga * 3 + 0] * w0 +
           A.coords[ga * 3 + 1] * w1 + A.coords[ga * 3 + 2] * w2 + cb;
    }
    A.feats0[row * D_ + d] = s / ((float)(end - start) + 1e-8f);
  }
  grid.sync();

  // ================= stage A (once): local MLP + layer-0 QKV (4 rows/block) =============
  {
    int w = tid >> 6, cp = tid & 63;
    int row = (bid << 2) + w;
    float* xs = sm.xs[w];
    float2 x2 = *(const float2*)(A.feats0 + (size_t)row * D_ + 2 * cp);
    xs[2 * cp] = x2.x; xs[2 * cp + 1] = x2.y;
    for (int l = 0; l < NLOCAL_; l++) {
      const unsigned int* W = A.lwb + l * 8192;
      float a0 = A.local_b[l * D_ + 2 * cp], a1 = A.local_b[l * D_ + 2 * cp + 1];
#pragma unroll 16
      for (int k = 0; k < 128; k++) {
        float x = xs[k];
        unsigned int pk = W[k * 64 + cp];
        a0 += x * bf_lo(pk); a1 += x * bf_hi(pk);
      }
      float y0 = gelu_tanh(a0) + xs[2 * cp];
      float y1 = gelu_tanh(a1) + xs[2 * cp + 1];
      xs[2 * cp] = y0; xs[2 * cp + 1] = y1;  // wave-lockstep safe
    }
    *(float2*)(A.featsL + (size_t)row * D_ + 2 * cp) = make_float2(xs[2 * cp], xs[2 * cp + 1]);
    qkv_from_xs(A, xs, row, cp, 0);
  }
  grid.sync();

  // ================= 3 iterations x 4 IPA layers =================
  for (int iter = 0; iter < NITER_; iter++) {
    for (int l = 0; l < NIPA_; l++) {
      // ---- attention: bid = bh*16 + qt ; 32 queries per block ----
      {
        int qt = bid & 15, bh = bid >> 4;
        int b = bh >> 3, h = bh & 7;
        const unsigned int* kbase = A.kb + (((h << 10) + (b << 9)) << 3);
        const unsigned int* vbase = A.vb + (((h << 10) + (b << 9)) << 3);
        for (int idx = tid; idx < NR_ * 8; idx += 256) {
          sm.a.ks[idx >> 3][idx & 7] = kbase[idx];
          sm.a.vs[idx >> 3][idx & 7] = vbase[idx];
        }
        for (int idx = tid; idx < NR_; idx += 256) {
          int gr = (b << 9) + idx;
          sm.a.ts[idx][0] = A.curT[gr * 3 + 0];
          sm.a.ts[idx][1] = A.curT[gr * 3 + 1];
          sm.a.ts[idx][2] = A.curT[gr * 3 + 2];
          sm.a.ms[idx] = A.res_mask[gr];
        }
        __syncthreads();
        float c0 = A.weff[l * 32 + h], c1 = A.weff[l * 32 + 8 + h];
        float c2 = A.weff[l * 32 + 16 + h], c3 = A.weff[l * 32 + 24 + h];
        float be = A.beff[l * 8 + h];
        int w = tid >> 6, lane = tid & 63;
        for (int it = 0; it < 8; it++) {
          int i = qt * 32 + w * 8 + it;
          float qreg[16];
          const float* qrow = A.qb + ((size_t)((b << 9) + i)) * D_ + h * DH_;
#pragma unroll
          for (int u = 0; u < 4; u++) {
            float4 q4 = *(const float4*)(qrow + 4 * u);
            qreg[4 * u] = q4.x; qreg[4 * u + 1] = q4.y;
            qreg[4 * u + 2] = q4.z; qreg[4 * u + 3] = q4.w;
          }
          float tix = sm.a.ts[i][0], tiy = sm.a.ts[i][1], tiz = sm.a.ts[i][2];
          float lsum = 0.f;
#pragma unroll
          for (int jj = 0; jj < 8; jj++) {
            int j = lane + 64 * jj;
            float dot = 0.f;
#pragma unroll
            for (int u = 0; u < 8; u++) {
              unsigned int pk = sm.a.ks[j][u];
              dot += qreg[2 * u] * bf_lo(pk) + qreg[2 * u + 1] * bf_hi(pk);
            }
            float rx = tix - sm.a.ts[j][0], ry = tiy - sm.a.ts[j][1], rz = tiz - sm.a.ts[j][2];
            float dist = sqrtf(rx * rx + ry * ry + rz * rz);
            float L = dot * 0.25f + c0 * rx + c1 * ry + c2 * rz + c3 * dist + be;
            if (sm.a.ms[j] <= 0.f) L = -1e9f;
            float p = __expf(L);  // shift-free: logits bounded, softmax shift-invariant
            sm.a.ps[w][j] = p;    // wave-private
            lsum += p;
          }
#pragma unroll
          for (int m = 1; m < 64; m <<= 1) lsum += __shfl_xor(lsum, m, 64);
          int d = lane & 7, jg = lane >> 3;
          float a0 = 0.f, a1 = 0.f;
#pragma unroll 8
          for (int t = 0; t < 64; t++) {
            int j = t * 8 + jg;
            float p = sm.a.ps[w][j];
            unsigned int pk = sm.a.vs[j][d];
            a0 += p * bf_lo(pk); a1 += p * bf_hi(pk);
          }
          a0 += __shfl_xor(a0, 8, 64); a0 += __shfl_xor(a0, 16, 64); a0 += __shfl_xor(a0, 32, 64);
          a1 += __shfl_xor(a1, 8, 64); a1 += __shfl_xor(a1, 16, 64); a1 += __shfl_xor(a1, 32, 64);
          if (jg == 0) {
            float inv = 1.f / lsum;
            *(float2*)(A.ob + ((size_t)((b << 9) + i)) * D_ + h * DH_ + 2 * d) =
                make_float2(a0 * inv, a1 * inv);
          }
        }
      }
      grid.sync();
      // ---- oproj + (qkv(l+1) | head [+ qkv0 for next iter]) : 4 rows/block ----
      {
        int w = tid >> 6, cp = tid & 63;
        int row = (bid << 2) + w;
        float* xs = sm.xs[w];
        float2 o2 = *(const float2*)(A.ob + (size_t)row * D_ + 2 * cp);
        xs[2 * cp] = o2.x; xs[2 * cp + 1] = o2.y;
        const unsigned int* W = A.wob + l * 8192;
        float a0 = A.bo[l * D_ + 2 * cp], a1 = A.bo[l * D_ + 2 * cp + 1];
#pragma unroll 16
        for (int k = 0; k < 128; k++) {
          float x = xs[k];
          unsigned int pk = W[k * 64 + cp];
          a0 += x * bf_lo(pk); a1 += x * bf_hi(pk);
        }
        const float* fin = (l == 0) ? A.featsL : A.featsW;
        float2 f2 = *(const float2*)(fin + (size_t)row * D_ + 2 * cp);
        float f0 = f2.x + a0, f1 = f2.y + a1;
        if (l < NIPA_ - 1) {
          *(float2*)(A.featsW + (size_t)row * D_ + 2 * cp) = make_float2(f0, f1);
          xs[2 * cp] = f0; xs[2 * cp + 1] = f1;  // lockstep safe
          qkv_from_xs(A, xs, row, cp, l + 1);
        } else {
          float pc[6];
#pragma unroll
          for (int c = 0; c < 6; c++)
            pc[c] = f0 * A.head_W[(2 * cp) * 6 + c] + f1 * A.head_W[(2 * cp + 1) * 6 + c];
#pragma unroll
          for (int m = 1; m < 64; m <<= 1)
#pragma unroll
            for (int c = 0; c < 6; c++) pc[c] += __shfl_xor(pc[c], m, 64);
          if (cp == 0) {
            float u[6];
#pragma unroll
            for (int c = 0; c < 6; c++) u[c] = pc[c] + A.head_b[c];
            float vx = u[0], vy = u[1], vz = u[2];
            float inv = rsqrtf(1.f + vx * vx + vy * vy + vz * vz);
            float qw = inv, qx = vx * inv, qy = vy * inv, qz = vz * inv;
            float Rd[9];
            Rd[0] = 1.f - 2.f * (qy * qy + qz * qz); Rd[1] = 2.f * (qx * qy - qw * qz);
            Rd[2] = 2.f * (qx * qz + qw * qy); Rd[3] = 2.f * (qx * qy + qw * qz);
            Rd[4] = 1.f - 2.f * (qx * qx + qz * qz); Rd[5] = 2.f * (qy * qz - qw * qx);
            Rd[6] = 2.f * (qx * qz - qw * qy); Rd[7] = 2.f * (qy * qz + qw * qx);
            Rd[8] = 1.f - 2.f * (qx * qx + qy * qy);
            float Ro[9];
#pragma unroll
            for (int c = 0; c < 9; c++) Ro[c] = A.curR[row * 9 + c];
            float Rn[9];
#pragma unroll
            for (int i2 = 0; i2 < 3; i2++)
#pragma unroll
              for (int kk = 0; kk < 3; kk++)
                Rn[i2 * 3 + kk] = Rd[i2 * 3 + 0] * Ro[0 * 3 + kk] +
                                  Rd[i2 * 3 + 1] * Ro[1 * 3 + kk] +
                                  Rd[i2 * 3 + 2] * Ro[2 * 3 + kk];
            float tx = A.curT[row * 3 + 0], ty = A.curT[row * 3 + 1], tz = A.curT[row * 3 + 2];
            float ux = u[3], uy = u[4], uz = u[5];
            float ntx = tx + Rn[0] * ux + Rn[1] * uy + Rn[2] * uz;
            float nty = ty + Rn[3] * ux + Rn[4] * uy + Rn[5] * uz;
            float ntz = tz + Rn[6] * ux + Rn[7] * uy + Rn[8] * uz;
            float m = A.res_mask[row];
#pragma unroll
            for (int c = 0; c < 9; c++) A.curR[row * 9 + c] = Rn[c];
            A.curT[row * 3 + 0] = ntx * m;
            A.curT[row * 3 + 1] = nty * m;
            A.curT[row * 3 + 2] = ntz * m;
          }
          if (iter < NITER_ - 1) {
            // recompute layer-0 qkv from featsL (constant across iterations)
            float2 fl = *(const float2*)(A.featsL + (size_t)row * D_ + 2 * cp);
            xs[2 * cp] = fl.x; xs[2 * cp + 1] = fl.y;  // lockstep safe
            qkv_from_xs(A, xs, row, cp, 0);
          }
        }
      }
      grid.sync();
    }
  }

  // ================= final frame composition + output =================
  {
    int a = gtid;
    if (a < B_ * NR_) {
#pragma unroll
      for (int c = 0; c < 9; c++) A.out[a * 9 + c] = A.curR[a * 9 + c];
      A.out[B_ * NR_ * 9 + a * 3 + 0] = A.curT[a * 3 + 0];
      A.out[B_ * NR_ * 9 + a * 3 + 1] = A.curT[a * 3 + 1];
      A.out[B_ * NR_ * 9 + a * 3 + 2] = A.curT[a * 3 + 2];
    }
    if (a < B_ * NA_) {
      int b = a / NA_;
      int r = b * NR_ + A.res_map[a];
      float x0 = A.coords[a * 3 + 0], x1 = A.coords[a * 3 + 1], x2 = A.coords[a * 3 + 2];
      float R0[9], Rc[9];
#pragma unroll
      for (int c = 0; c < 9; c++) { R0[c] = A.rots_bad[r * 9 + c]; Rc[c] = A.curR[r * 9 + c]; }
      float t0x = A.trans_bad[r * 3 + 0], t0y = A.trans_bad[r * 3 + 1];
      float t0z = A.trans_bad[r * 3 + 2];
      float dx = x0 - t0x, dy = x1 - t0y, dz = x2 - t0z;
      float lx = R0[0] * dx + R0[3] * dy + R0[6] * dz;
      float ly = R0[1] * dx + R0[4] * dy + R0[7] * dz;
      float lz = R0[2] * dx + R0[5] * dy + R0[8] * dz;
      float tcx = A.curT[r * 3 + 0], tcy = A.curT[r * 3 + 1], tcz = A.curT[r * 3 + 2];
      float fx = Rc[0] * lx + Rc[3] * ly + Rc[6] * lz + tcx;
      float fy = Rc[1] * lx + Rc[4] * ly + Rc[7] * lz + tcy;
      float fz = Rc[2] * lx + Rc[5] * ly + Rc[8] * lz + tcz;
      int off = B_ * NR_ * 12;
      A.out[off + a * 3 + 0] = fx;
      A.out[off + a * 3 + 1] = fy;
      A.out[off + a * 3 + 2] = fz;
    }
  }
}

extern "C" void kernel_launch(void* const* d_in, const int* in_sizes, int n_in,
                              void* d_out, int out_size, void* d_ws, size_t ws_size,
                              hipStream_t stream) {
  Args A;
  A.coords    = (const float*)d_in[0];
  A.atype     = (const int*)d_in[1];
  A.rtype     = (const int*)d_in[2];
  // d_in[3] = mask (unused)
  A.res_mask  = (const float*)d_in[4];
  A.res_map   = (const int*)d_in[5];
  A.rots_bad  = (const float*)d_in[6];
  A.trans_bad = (const float*)d_in[7];
  A.atom_emb  = (const float*)d_in[8];
  A.res_emb   = (const float*)d_in[9];
  A.coord_W   = (const float*)d_in[10];
  A.coord_b   = (const float*)d_in[11];
  A.local_W   = (const float*)d_in[12];
  A.local_b   = (const float*)d_in[13];
  A.pair_W    = (const float*)d_in[14];
  A.pair_b    = (const float*)d_in[15];
  A.Wq        = (const float*)d_in[16];
  A.Wk        = (const float*)d_in[17];
  A.Wv        = (const float*)d_in[18];
  A.Wb        = (const float*)d_in[19];
  A.Wo        = (const float*)d_in[20];
  A.bo        = (const float*)d_in[21];
  A.head_W    = (const float*)d_in[22];
  A.head_b    = (const float*)d_in[23];

  // ws layout: matches round-3's proven footprint (~3.36 MB)
  float* ws = (float*)d_ws;
  A.ob     = ws;  ws += 131072;   // aliased: feats0 (stage P/A) then ob (IPA)
  A.feats0 = A.ob;
  A.featsL = ws;  ws += 131072;
  A.featsW = ws;  ws += 131072;
  A.qb     = ws;  ws += 131072;
  A.weff   = ws;  ws += 128;
  A.beff   = ws;  ws += 32;
  A.curR   = ws;  ws += 9216;
  A.curT   = ws;  ws += 3072;
  unsigned int* wu = (unsigned int*)ws;
  A.kb   = wu;  wu += 65536;
  A.vb   = wu;  wu += 65536;
  A.lwb  = wu;  wu += 40960;
  A.qkvb = wu;  wu += 98304;
  A.wob  = wu;  wu += 32768;
  A.out = (float*)d_out;

  void* args[] = {&A};
  hipLaunchCooperativeKernel((void*)mega, dim3(256), dim3(256), args, 0, stream);
}

// Round 6
// 535.210 us; speedup vs baseline: 3.5385x; 3.5385x over previous
//
#include <hip/hip_runtime.h>
#include <math.h>

#define B_ 2
#define NA_ 4096
#define NR_ 512
#define D_ 128
#define H_ 8
#define DH_ 16
#define NLOCAL_ 5
#define NIPA_ 4
#define NITER_ 3

__device__ __forceinline__ float gelu_tanh(float x) {
  float x3 = x * x * x;
  return 0.5f * x * (1.0f + tanhf(0.7978845608028654f * (x + 0.044715f * x3)));
}
__device__ __forceinline__ unsigned int pack_bf(float lo, float hi) {
  unsigned int a = __float_as_uint(lo);
  unsigned int b = __float_as_uint(hi);
  a = (a + 0x7fffu + ((a >> 16) & 1u)) >> 16;
  b = (b + 0x7fffu + ((b >> 16) & 1u)) & 0xffff0000u;
  return b | a;
}
__device__ __forceinline__ float bf_lo(unsigned int u) { return __uint_as_float(u << 16); }
__device__ __forceinline__ float bf_hi(unsigned int u) { return __uint_as_float(u & 0xffff0000u); }

// one wave: q,k,v row projections for layer ln from xs (LDS, 128 floats) into qb/kw/vw
__device__ __forceinline__ void qkv_from_xs(const float* xs, const unsigned int* qkvb,
                                            float* qb, unsigned int* kw, unsigned int* vw,
                                            int row, int cp, int ln) {
#pragma unroll
  for (int m = 0; m < 3; m++) {
    const unsigned int* Wm = qkvb + (ln * 3 + m) * 8192;
    float b0 = 0.f, b1 = 0.f;
#pragma unroll 16
    for (int k = 0; k < 128; k++) {
      float x = xs[k];
      unsigned int pk = Wm[k * 64 + cp];
      b0 += x * bf_lo(pk); b1 += x * bf_hi(pk);
    }
    if (m == 0)
      *(float2*)(qb + (size_t)row * D_ + 2 * cp) = make_float2(b0, b1);
    else {
      int h = cp >> 3, u = cp & 7;
      unsigned int pk = pack_bf(b0, b1);
      if (m == 1) kw[((h << 10) + row) * 8 + u] = pk;
      else vw[((h << 10) + row) * 8 + u] = pk;
    }
  }
}

// ============ setup: weight pack + weff + pooling + frame init ============
__global__ __launch_bounds__(256) void k_setup(
    const float* __restrict__ coords, const int* __restrict__ atype,
    const int* __restrict__ rtype, const int* __restrict__ res_map,
    const float* __restrict__ rots_bad, const float* __restrict__ trans_bad,
    const float* __restrict__ atom_emb, const float* __restrict__ res_emb,
    const float* __restrict__ coord_W, const float* __restrict__ coord_b,
    const float* __restrict__ local_W, const float* __restrict__ pair_W,
    const float* __restrict__ pair_b, const float* __restrict__ Wq,
    const float* __restrict__ Wk, const float* __restrict__ Wv, const float* __restrict__ Wb,
    const float* __restrict__ Wo, float* __restrict__ feats0, float* __restrict__ weff,
    float* __restrict__ beff, float* __restrict__ curR, float* __restrict__ curT0,
    unsigned int* __restrict__ lwb, unsigned int* __restrict__ qkvb,
    unsigned int* __restrict__ wob) {
  int tid = threadIdx.x, bid = blockIdx.x;
  int gtid = (bid << 8) + tid;
  for (int t = gtid; t < 172032; t += 65536) {
    if (t < 40960) {
      int cp = t & 63, k = (t >> 6) & 127, l = t >> 13;
      const float* s = local_W + ((size_t)(l * 128 + k) * 128 + 2 * cp);
      lwb[t] = pack_bf(s[0], s[1]);
    } else if (t < 139264) {
      int t2 = t - 40960;
      int l = t2 / 24576, rem = t2 % 24576;
      int m = rem >> 13, k = (rem >> 6) & 127, cp = rem & 63;
      const float* base = (m == 0) ? Wq : ((m == 1) ? Wk : Wv);
      const float* s = base + ((size_t)l * 16384 + k * 128 + 2 * cp);
      qkvb[t2] = pack_bf(s[0], s[1]);
    } else {
      int t3 = t - 139264;
      int l = t3 >> 13, k = (t3 >> 6) & 127, cp = t3 & 63;
      const float* s = Wo + ((size_t)l * 16384 + k * 128 + 2 * cp);
      wob[t3] = pack_bf(s[0], s[1]);
    }
  }
  if (gtid < 160) {
    int l = gtid / 40, rest = gtid % 40;
    int c = rest / 8, h = rest & 7;
    const float* row = (c < 4) ? (pair_W + c * D_) : pair_b;
    float acc = 0.f;
    for (int d = 0; d < D_; d++) acc += row[d] * Wb[l * D_ * H_ + d * H_ + h];
    if (c < 4) weff[l * 32 + c * 8 + h] = acc;
    else beff[l * 8 + h] = acc;
  }
  if (gtid < 9216) curR[gtid] = rots_bad[gtid];
  else if (gtid < 12288) curT0[gtid - 9216] = trans_bad[gtid - 9216];
  for (int rp = 0; rp < 2; rp++) {
    int row = (bid << 2) + (rp << 1) + (tid >> 7);
    int d = tid & 127;
    int b = row >> 9, rr = row & (NR_ - 1);
    const int* rm = res_map + b * NA_;
    int lo = 0, hi = NA_;
    while (lo < hi) { int mid = (lo + hi) >> 1; if (rm[mid] < rr) lo = mid + 1; else hi = mid; }
    int start = lo;
    hi = NA_;
    while (lo < hi) { int mid = (lo + hi) >> 1; if (rm[mid] < rr + 1) lo = mid + 1; else hi = mid; }
    int end = lo;
    float w0 = coord_W[d], w1 = coord_W[D_ + d], w2 = coord_W[2 * D_ + d], cb = coord_b[d];
    float s = 0.f;
    for (int a = start; a < end; a++) {
      int ga = b * NA_ + a;
      s += atom_emb[atype[ga] * D_ + d] + res_emb[rtype[ga] * D_ + d] +
           coords[ga * 3 + 0] * w0 + coords[ga * 3 + 1] * w1 + coords[ga * 3 + 2] * w2 + cb;
    }
    feats0[row * D_ + d] = s / ((float)(end - start) + 1e-8f);
  }
}

// ============ stage A (once): local MLP + layer-0 QKV, 4 rows/block ============
__global__ __launch_bounds__(256) void k_localA(
    const float* __restrict__ feats0, const unsigned int* __restrict__ lwb,
    const float* __restrict__ local_b, const unsigned int* __restrict__ qkvb,
    float* __restrict__ featsL, float* __restrict__ qb, unsigned int* __restrict__ kw,
    unsigned int* __restrict__ vw) {
  __shared__ float xs[4][D_];
  int tid = threadIdx.x;
  int w = tid >> 6, cp = tid & 63;
  int row = (blockIdx.x << 2) + w;
  float2 x2 = *(const float2*)(feats0 + (size_t)row * D_ + 2 * cp);
  xs[w][2 * cp] = x2.x; xs[w][2 * cp + 1] = x2.y;
  for (int l = 0; l < NLOCAL_; l++) {
    const unsigned int* W = lwb + l * 8192;
    float a0 = local_b[l * D_ + 2 * cp], a1 = local_b[l * D_ + 2 * cp + 1];
#pragma unroll 16
    for (int k = 0; k < 128; k++) {
      float x = xs[w][k];
      unsigned int pk = W[k * 64 + cp];
      a0 += x * bf_lo(pk); a1 += x * bf_hi(pk);
    }
    float y0 = gelu_tanh(a0) + xs[w][2 * cp];
    float y1 = gelu_tanh(a1) + xs[w][2 * cp + 1];
    xs[w][2 * cp] = y0; xs[w][2 * cp + 1] = y1;  // wave-lockstep safe
  }
  *(float2*)(featsL + (size_t)row * D_ + 2 * cp) = make_float2(xs[w][2 * cp], xs[w][2 * cp + 1]);
  qkv_from_xs(xs[w], qkvb, qb, kw, vw, row, cp, 0);
}

// ============ fused IPA layer: attention(all heads) + oproj + {qkv(l+1) | head} ============
__global__ __launch_bounds__(256) void k_layer(
    float* __restrict__ qb, const unsigned int* __restrict__ kr,
    const unsigned int* __restrict__ vr, unsigned int* __restrict__ kw,
    unsigned int* __restrict__ vw, const float* __restrict__ featsL,
    float* __restrict__ featsW, const float* __restrict__ curT_r, float* __restrict__ curT_w,
    float* __restrict__ curR, const float* __restrict__ res_mask,
    const float* __restrict__ weff, const float* __restrict__ beff,
    const unsigned int* __restrict__ wob, const unsigned int* __restrict__ qkvb,
    const float* __restrict__ bo, const float* __restrict__ head_W,
    const float* __restrict__ head_b, int l, int lastLayer, int doQ0) {
  __shared__ float ts[NR_][3];
  __shared__ float msk[NR_];
  __shared__ float os[4][D_];
  int tid = threadIdx.x, bid = blockIdx.x;
  int w = tid >> 6, lane = tid & 63;
  int row = (bid << 2) + w;            // 0..1023
  int b = bid >> 7;                    // batch (same for whole block)

  for (int idx = tid; idx < NR_; idx += 256) {
    int gr = (b << 9) + idx;
    ts[idx][0] = curT_r[gr * 3 + 0];
    ts[idx][1] = curT_r[gr * 3 + 1];
    ts[idx][2] = curT_r[gr * 3 + 2];
    msk[idx] = res_mask[gr];
  }
  __syncthreads();

  // ---- attention: lane = h*8 + jg ; j = t*8 + jg ----
  int h = lane >> 3, jg = lane & 7;
  float qreg[16];
  {
    const float* qrow = qb + (size_t)row * D_ + h * DH_;
#pragma unroll
    for (int u = 0; u < 4; u++) {
      float4 q4 = *(const float4*)(qrow + 4 * u);
      qreg[4 * u] = q4.x; qreg[4 * u + 1] = q4.y;
      qreg[4 * u + 2] = q4.z; qreg[4 * u + 3] = q4.w;
    }
  }
  int il = row & (NR_ - 1);
  float tix = ts[il][0], tiy = ts[il][1], tiz = ts[il][2];
  float c0 = weff[l * 32 + h], c1 = weff[l * 32 + 8 + h];
  float c2 = weff[l * 32 + 16 + h], c3 = weff[l * 32 + 24 + h];
  float be = beff[l * 8 + h];
  const uint4* kp = (const uint4*)(kr + ((size_t)((h << 10) + (b << 9))) * 8);
  const uint4* vp = (const uint4*)(vr + ((size_t)((h << 10) + (b << 9))) * 8);

  float oacc[16];
#pragma unroll
  for (int d = 0; d < 16; d++) oacc[d] = 0.f;
  float lsum = 0.f;

#pragma unroll 4
  for (int t = 0; t < 64; t++) {
    int j = t * 8 + jg;
    uint4 k0 = kp[j * 2], k1 = kp[j * 2 + 1];
    uint4 v0 = vp[j * 2], v1 = vp[j * 2 + 1];
    float dot = qreg[0] * bf_lo(k0.x) + qreg[1] * bf_hi(k0.x) +
                qreg[2] * bf_lo(k0.y) + qreg[3] * bf_hi(k0.y) +
                qreg[4] * bf_lo(k0.z) + qreg[5] * bf_hi(k0.z) +
                qreg[6] * bf_lo(k0.w) + qreg[7] * bf_hi(k0.w) +
                qreg[8] * bf_lo(k1.x) + qreg[9] * bf_hi(k1.x) +
                qreg[10] * bf_lo(k1.y) + qreg[11] * bf_hi(k1.y) +
                qreg[12] * bf_lo(k1.z) + qreg[13] * bf_hi(k1.z) +
                qreg[14] * bf_lo(k1.w) + qreg[15] * bf_hi(k1.w);
    float rx = tix - ts[j][0], ry = tiy - ts[j][1], rz = tiz - ts[j][2];
    float dist = sqrtf(rx * rx + ry * ry + rz * rz);
    float L = dot * 0.25f + c0 * rx + c1 * ry + c2 * rz + c3 * dist + be;
    if (msk[j] <= 0.f) L = -1e9f;
    float p = __expf(L);  // shift-free: logits bounded, softmax shift-invariant
    lsum += p;
    oacc[0] += p * bf_lo(v0.x);  oacc[1] += p * bf_hi(v0.x);
    oacc[2] += p * bf_lo(v0.y);  oacc[3] += p * bf_hi(v0.y);
    oacc[4] += p * bf_lo(v0.z);  oacc[5] += p * bf_hi(v0.z);
    oacc[6] += p * bf_lo(v0.w);  oacc[7] += p * bf_hi(v0.w);
    oacc[8] += p * bf_lo(v1.x);  oacc[9] += p * bf_hi(v1.x);
    oacc[10] += p * bf_lo(v1.y); oacc[11] += p * bf_hi(v1.y);
    oacc[12] += p * bf_lo(v1.z); oacc[13] += p * bf_hi(v1.z);
    oacc[14] += p * bf_lo(v1.w); oacc[15] += p * bf_hi(v1.w);
  }
  // reduce over jg lanes (bits 0..2)
#pragma unroll
  for (int m = 1; m < 8; m <<= 1) {
    lsum += __shfl_xor(lsum, m, 64);
#pragma unroll
    for (int d = 0; d < 16; d++) oacc[d] += __shfl_xor(oacc[d], m, 64);
  }
  if (jg == 0) {
    float inv = 1.f / lsum;
#pragma unroll
    for (int d = 0; d < 16; d++) os[w][h * 16 + d] = oacc[d] * inv;
  }
  // os[w] is wave-private -> no barrier (lockstep wave)

  // ---- oproj + residual ----
  int cp = lane;
  const unsigned int* Wp = wob + l * 8192;
  float a0 = bo[l * D_ + 2 * cp], a1 = bo[l * D_ + 2 * cp + 1];
#pragma unroll 16
  for (int k = 0; k < 128; k++) {
    float x = os[w][k];
    unsigned int pk = Wp[k * 64 + cp];
    a0 += x * bf_lo(pk); a1 += x * bf_hi(pk);
  }
  const float* fin = (l == 0) ? featsL : featsW;
  float2 f2 = *(const float2*)(fin + (size_t)row * D_ + 2 * cp);
  float f0 = f2.x + a0, f1 = f2.y + a1;
  *(float2*)(featsW + (size_t)row * D_ + 2 * cp) = make_float2(f0, f1);

  if (!lastLayer) {
    os[w][2 * cp] = f0; os[w][2 * cp + 1] = f1;  // lockstep safe
    qkv_from_xs(os[w], qkvb, qb, kw, vw, row, cp, l + 1);
  } else {
    // head projection + frame update
    float pc[6];
#pragma unroll
    for (int c = 0; c < 6; c++)
      pc[c] = f0 * head_W[(2 * cp) * 6 + c] + f1 * head_W[(2 * cp + 1) * 6 + c];
#pragma unroll
    for (int m = 1; m < 64; m <<= 1)
#pragma unroll
      for (int c = 0; c < 6; c++) pc[c] += __shfl_xor(pc[c], m, 64);
    if (cp == 0) {
      float u[6];
#pragma unroll
      for (int c = 0; c < 6; c++) u[c] = pc[c] + head_b[c];
      float vx = u[0], vy = u[1], vz = u[2];
      float inv = rsqrtf(1.f + vx * vx + vy * vy + vz * vz);
      float qw = inv, qx = vx * inv, qy = vy * inv, qz = vz * inv;
      float Rd[9];
      Rd[0] = 1.f - 2.f * (qy * qy + qz * qz); Rd[1] = 2.f * (qx * qy - qw * qz);
      Rd[2] = 2.f * (qx * qz + qw * qy); Rd[3] = 2.f * (qx * qy + qw * qz);
      Rd[4] = 1.f - 2.f * (qx * qx + qz * qz); Rd[5] = 2.f * (qy * qz - qw * qx);
      Rd[6] = 2.f * (qx * qz - qw * qy); Rd[7] = 2.f * (qy * qz + qw * qx);
      Rd[8] = 1.f - 2.f * (qx * qx + qy * qy);
      float Ro[9];
#pragma unroll
      for (int c = 0; c < 9; c++) Ro[c] = curR[row * 9 + c];
      float Rn[9];
#pragma unroll
      for (int i2 = 0; i2 < 3; i2++)
#pragma unroll
        for (int kk = 0; kk < 3; kk++)
          Rn[i2 * 3 + kk] = Rd[i2 * 3 + 0] * Ro[0 * 3 + kk] + Rd[i2 * 3 + 1] * Ro[1 * 3 + kk] +
                            Rd[i2 * 3 + 2] * Ro[2 * 3 + kk];
      float tx = curT_r[row * 3 + 0], ty = curT_r[row * 3 + 1], tz = curT_r[row * 3 + 2];
      float ux = u[3], uy = u[4], uz = u[5];
      float m = res_mask[row];
#pragma unroll
      for (int c = 0; c < 9; c++) curR[row * 9 + c] = Rn[c];
      curT_w[row * 3 + 0] = (tx + Rn[0] * ux + Rn[1] * uy + Rn[2] * uz) * m;
      curT_w[row * 3 + 1] = (ty + Rn[3] * ux + Rn[4] * uy + Rn[5] * uz) * m;
      curT_w[row * 3 + 2] = (tz + Rn[6] * ux + Rn[7] * uy + Rn[8] * uz) * m;
    }
    if (doQ0) {
      float2 fl = *(const float2*)(featsL + (size_t)row * D_ + 2 * cp);
      os[w][2 * cp] = fl.x; os[w][2 * cp + 1] = fl.y;  // lockstep safe
      qkv_from_xs(os[w], qkvb, qb, kw, vw, row, cp, 0);
    }
  }
}

// ============ final frame composition + output ============
__global__ void k_final(const float* __restrict__ coords, const int* __restrict__ res_map,
                        const float* __restrict__ rots_bad, const float* __restrict__ trans_bad,
                        const float* __restrict__ curR, const float* __restrict__ curT,
                        float* __restrict__ out) {
  int a = blockIdx.x * blockDim.x + threadIdx.x;
  if (a < B_ * NR_) {
#pragma unroll
    for (int c = 0; c < 9; c++) out[a * 9 + c] = curR[a * 9 + c];
    out[B_ * NR_ * 9 + a * 3 + 0] = curT[a * 3 + 0];
    out[B_ * NR_ * 9 + a * 3 + 1] = curT[a * 3 + 1];
    out[B_ * NR_ * 9 + a * 3 + 2] = curT[a * 3 + 2];
  }
  if (a >= B_ * NA_) return;
  int b = a / NA_;
  int r = b * NR_ + res_map[a];
  float x0 = coords[a * 3 + 0], x1 = coords[a * 3 + 1], x2 = coords[a * 3 + 2];
  float R0[9], Rc[9];
#pragma unroll
  for (int c = 0; c < 9; c++) { R0[c] = rots_bad[r * 9 + c]; Rc[c] = curR[r * 9 + c]; }
  float t0x = trans_bad[r * 3 + 0], t0y = trans_bad[r * 3 + 1], t0z = trans_bad[r * 3 + 2];
  float dx = x0 - t0x, dy = x1 - t0y, dz = x2 - t0z;
  float lx = R0[0] * dx + R0[3] * dy + R0[6] * dz;
  float ly = R0[1] * dx + R0[4] * dy + R0[7] * dz;
  float lz = R0[2] * dx + R0[5] * dy + R0[8] * dz;
  float tcx = curT[r * 3 + 0], tcy = curT[r * 3 + 1], tcz = curT[r * 3 + 2];
  float fx = Rc[0] * lx + Rc[3] * ly + Rc[6] * lz + tcx;
  float fy = Rc[1] * lx + Rc[4] * ly + Rc[7] * lz + tcy;
  float fz = Rc[2] * lx + Rc[5] * ly + Rc[8] * lz + tcz;
  int off = B_ * NR_ * 12;
  out[off + a * 3 + 0] = fx;
  out[off + a * 3 + 1] = fy;
  out[off + a * 3 + 2] = fz;
}

extern "C" void kernel_launch(void* const* d_in, const int* in_sizes, int n_in,
                              void* d_out, int out_size, void* d_ws, size_t ws_size,
                              hipStream_t stream) {
  const float* coords    = (const float*)d_in[0];
  const int*   atype     = (const int*)d_in[1];
  const int*   rtype     = (const int*)d_in[2];
  // d_in[3] = mask (unused)
  const float* res_mask  = (const float*)d_in[4];
  const int*   res_map   = (const int*)d_in[5];
  const float* rots_bad  = (const float*)d_in[6];
  const float* trans_bad = (const float*)d_in[7];
  const float* atom_emb  = (const float*)d_in[8];
  const float* res_emb   = (const float*)d_in[9];
  const float* coord_W   = (const float*)d_in[10];
  const float* coord_b   = (const float*)d_in[11];
  const float* local_W   = (const float*)d_in[12];
  const float* local_b   = (const float*)d_in[13];
  const float* pair_W    = (const float*)d_in[14];
  const float* pair_b    = (const float*)d_in[15];
  const float* Wq        = (const float*)d_in[16];
  const float* Wk        = (const float*)d_in[17];
  const float* Wv        = (const float*)d_in[18];
  const float* Wb        = (const float*)d_in[19];
  const float* Wo        = (const float*)d_in[20];
  const float* bo        = (const float*)d_in[21];
  const float* head_W    = (const float*)d_in[22];
  const float* head_b    = (const float*)d_in[23];

  float* ws = (float*)d_ws;
  float* qb     = ws;  ws += 131072;   // aliased: feats0 (setup/localA), then q
  float* feats0 = qb;
  float* featsL = ws;  ws += 131072;
  float* featsW = ws;  ws += 131072;
  float* weff   = ws;  ws += 128;
  float* beff   = ws;  ws += 32;
  float* curR   = ws;  ws += 9216;
  float* curT0  = ws;  ws += 3072;
  float* curT1  = ws;  ws += 3072;
  unsigned int* wu = (unsigned int*)ws;
  unsigned int* kbA = wu;  wu += 65536;
  unsigned int* vbA = wu;  wu += 65536;
  unsigned int* kbB = wu;  wu += 65536;
  unsigned int* vbB = wu;  wu += 65536;
  unsigned int* lwb  = wu; wu += 40960;
  unsigned int* qkvb = wu; wu += 98304;
  unsigned int* wob  = wu; wu += 32768;
  float* out = (float*)d_out;

  k_setup<<<256, 256, 0, stream>>>(coords, atype, rtype, res_map, rots_bad, trans_bad,
                                   atom_emb, res_emb, coord_W, coord_b, local_W, pair_W,
                                   pair_b, Wq, Wk, Wv, Wb, Wo, feats0, weff, beff, curR,
                                   curT0, lwb, qkvb, wob);
  k_localA<<<256, 256, 0, stream>>>(feats0, lwb, local_b, qkvb, featsL, qb, kbA, vbA);

  for (int iter = 0; iter < NITER_; iter++) {
    float* Tr = (iter & 1) ? curT1 : curT0;
    float* Tw = (iter & 1) ? curT0 : curT1;
    for (int l = 0; l < NIPA_; l++) {
      unsigned int* krd = (l & 1) ? kbB : kbA;
      unsigned int* vrd = (l & 1) ? vbB : vbA;
      unsigned int* kwr = (l & 1) ? kbA : kbB;
      unsigned int* vwr = (l & 1) ? vbA : vbB;
      k_layer<<<256, 256, 0, stream>>>(qb, krd, vrd, kwr, vwr, featsL, featsW, Tr, Tw, curR,
                                       res_mask, weff, beff, wob, qkvb, bo, head_W, head_b,
                                       l, (l == NIPA_ - 1) ? 1 : 0,
                                       (l == NIPA_ - 1 && iter < NITER_ - 1) ? 1 : 0);
    }
  }
  // final curT lives in the buffer written by iter 2 (Tw of iter2 = curT1)
  k_final<<<(B_ * NA_ + 255) / 256, 256, 0, stream>>>(coords, res_map, rots_bad, trans_bad,
                                                      curR, curT1, out);
}

// Round 7
// 411.717 us; speedup vs baseline: 4.5999x; 1.2999x over previous
//
#include <hip/hip_runtime.h>
#include <math.h>

#define B_ 2
#define NA_ 4096
#define NR_ 512
#define D_ 128
#define H_ 8
#define DH_ 16
#define NLOCAL_ 5
#define NIPA_ 4
#define NITER_ 3

typedef _Float16 half2_t __attribute__((ext_vector_type(2)));

#if __has_builtin(__builtin_amdgcn_fdot2)
#define FDOT2(a, b, c) __builtin_amdgcn_fdot2((a), (b), (c), false)
#else
__device__ __forceinline__ float FDOT2(half2_t a, half2_t b, float c) {
  return c + (float)a.x * (float)b.x + (float)a.y * (float)b.y;
}
#endif

__device__ __forceinline__ unsigned int pack_h(float a, float b) {
  union { unsigned int u; half2_t h; } x;
  x.h = half2_t{(_Float16)a, (_Float16)b};
  return x.u;
}
__device__ __forceinline__ half2_t u2h(unsigned int u) {
  union { unsigned int u; half2_t h; } x;
  x.u = u;
  return x.h;
}
__device__ __forceinline__ float gelu_tanh(float x) {
  float x3 = x * x * x;
  return 0.5f * x * (1.0f + tanhf(0.7978845608028654f * (x + 0.044715f * x3)));
}

// ============ setup: weight pack (f16 k-pair-major) + weff + pooling + frame init ========
__global__ __launch_bounds__(256) void k_setup(
    const float* __restrict__ coords, const int* __restrict__ atype,
    const int* __restrict__ rtype, const int* __restrict__ res_map,
    const float* __restrict__ rots_bad, const float* __restrict__ trans_bad,
    const float* __restrict__ atom_emb, const float* __restrict__ res_emb,
    const float* __restrict__ coord_W, const float* __restrict__ coord_b,
    const float* __restrict__ local_W, const float* __restrict__ pair_W,
    const float* __restrict__ pair_b, const float* __restrict__ Wq,
    const float* __restrict__ Wk, const float* __restrict__ Wv, const float* __restrict__ Wb,
    const float* __restrict__ Wo, float* __restrict__ feats0, float* __restrict__ weff,
    float* __restrict__ beff, float* __restrict__ curR, float* __restrict__ curT0,
    unsigned int* __restrict__ lwh, unsigned int* __restrict__ qkvh,
    unsigned int* __restrict__ woh) {
  int tid = threadIdx.x, bid = blockIdx.x;
  int gtid = (bid << 8) + tid;
  // layouts: lwh[l][kk][c] = half2(W[2kk][c], W[2kk+1][c]) etc.
  for (int t = gtid; t < 172032; t += 65536) {
    if (t < 40960) {
      int c = t & 127, kk = (t >> 7) & 63, l = t >> 13;
      const float* s = local_W + (size_t)l * 16384 + (2 * kk) * 128 + c;
      lwh[t] = pack_h(s[0], s[128]);
    } else if (t < 139264) {
      int t2 = t - 40960;
      int c = t2 & 127, kk = (t2 >> 7) & 63, lm = t2 >> 13;
      int l = lm / 3, m = lm % 3;
      const float* base = (m == 0) ? Wq : ((m == 1) ? Wk : Wv);
      const float* s = base + (size_t)l * 16384 + (2 * kk) * 128 + c;
      qkvh[t2] = pack_h(s[0], s[128]);
    } else {
      int t3 = t - 139264;
      int c = t3 & 127, kk = (t3 >> 7) & 63, l = t3 >> 13;
      const float* s = Wo + (size_t)l * 16384 + (2 * kk) * 128 + c;
      woh[t3] = pack_h(s[0], s[128]);
    }
  }
  if (gtid < 160) {
    int l = gtid / 40, rest = gtid % 40;
    int c = rest / 8, h = rest & 7;
    const float* row = (c < 4) ? (pair_W + c * D_) : pair_b;
    float acc = 0.f;
    for (int d = 0; d < D_; d++) acc += row[d] * Wb[l * D_ * H_ + d * H_ + h];
    if (c < 4) weff[l * 32 + c * 8 + h] = acc;
    else beff[l * 8 + h] = acc;
  }
  if (gtid < 9216) curR[gtid] = rots_bad[gtid];
  else if (gtid < 12288) curT0[gtid - 9216] = trans_bad[gtid - 9216];
  for (int rp = 0; rp < 2; rp++) {
    int row = (bid << 2) + (rp << 1) + (tid >> 7);
    int d = tid & 127;
    int b = row >> 9, rr = row & (NR_ - 1);
    const int* rm = res_map + b * NA_;
    int lo = 0, hi = NA_;
    while (lo < hi) { int mid = (lo + hi) >> 1; if (rm[mid] < rr) lo = mid + 1; else hi = mid; }
    int start = lo;
    hi = NA_;
    while (lo < hi) { int mid = (lo + hi) >> 1; if (rm[mid] < rr + 1) lo = mid + 1; else hi = mid; }
    int end = lo;
    float w0 = coord_W[d], w1 = coord_W[D_ + d], w2 = coord_W[2 * D_ + d], cb = coord_b[d];
    float s = 0.f;
    for (int a = start; a < end; a++) {
      int ga = b * NA_ + a;
      s += atom_emb[atype[ga] * D_ + d] + res_emb[rtype[ga] * D_ + d] +
           coords[ga * 3 + 0] * w0 + coords[ga * 3 + 1] * w1 + coords[ga * 3 + 2] * w2 + cb;
    }
    feats0[row * D_ + d] = s / ((float)(end - start) + 1e-8f);
  }
}

// ============ localA: 5-layer MLP + layer-0 QKV ; 1 row/block, 4 waves ============
__global__ __launch_bounds__(256) void k_localA(
    const float* __restrict__ feats0, const unsigned int* __restrict__ lwh,
    const float* __restrict__ local_b, const unsigned int* __restrict__ qkvh,
    float* __restrict__ featsL, unsigned int* __restrict__ qbU,
    unsigned int* __restrict__ kw, unsigned int* __restrict__ vw) {
  __shared__ float part[4][128];
  __shared__ float xsf[128];
  __shared__ unsigned int xh[64];
  int row = blockIdx.x;
  int tid = threadIdx.x;
  int w = tid >> 6, cp = tid & 63;
  if (tid < 128) xsf[tid] = feats0[row * D_ + tid];
  __syncthreads();
  if (tid < 64) xh[tid] = pack_h(xsf[2 * tid], xsf[2 * tid + 1]);
  __syncthreads();
  for (int l = 0; l < NLOCAL_; l++) {
    const unsigned int* W = lwh + (l * 64) * 128;
    float a0 = 0.f, a1 = 0.f;
#pragma unroll
    for (int kk = 0; kk < 16; kk++) {
      int k = w * 16 + kk;
      uint2 ww = *(const uint2*)(W + k * 128 + 2 * cp);
      half2_t x = u2h(xh[k]);
      a0 = FDOT2(x, u2h(ww.x), a0);
      a1 = FDOT2(x, u2h(ww.y), a1);
    }
    *(float2*)&part[w][2 * cp] = make_float2(a0, a1);
    __syncthreads();
    if (tid < 128) {
      float s = part[0][tid] + part[1][tid] + part[2][tid] + part[3][tid] + local_b[l * D_ + tid];
      xsf[tid] = gelu_tanh(s) + xsf[tid];
    }
    __syncthreads();
    if (tid < 64) xh[tid] = pack_h(xsf[2 * tid], xsf[2 * tid + 1]);
    __syncthreads();
  }
  if (tid < 128) featsL[row * D_ + tid] = xsf[tid];
  if (w < 3) {
    const unsigned int* Wm = qkvh + (size_t)(0 * 3 + w) * 8192;
    float b0 = 0.f, b1 = 0.f;
#pragma unroll 16
    for (int kk = 0; kk < 64; kk++) {
      uint2 ww = *(const uint2*)(Wm + kk * 128 + 2 * cp);
      half2_t x = u2h(xh[kk]);
      b0 = FDOT2(x, u2h(ww.x), b0);
      b1 = FDOT2(x, u2h(ww.y), b1);
    }
    unsigned int pk = pack_h(b0, b1);
    int h = cp >> 3, u = cp & 7;
    if (w == 0) qbU[row * 64 + cp] = pk;
    else if (w == 1) kw[((h << 10) + row) * 8 + u] = pk;
    else vw[((h << 10) + row) * 8 + u] = pk;
  }
}

// ============ attention: block=(b,h,qt16), 8 waves, 2 q/wave; K/V f16 in LDS ============
__global__ __launch_bounds__(512) void k_attn(
    const unsigned int* __restrict__ qbU, const unsigned int* __restrict__ kr,
    const unsigned int* __restrict__ vr, const float* __restrict__ curT_r,
    const float* __restrict__ res_mask, const float* __restrict__ weff,
    const float* __restrict__ beff, float* __restrict__ ob, int l) {
  __shared__ unsigned int ks[NR_][9];  // pad 9: stride 9 coprime 32 -> conflict-free
  __shared__ unsigned int vs[NR_][9];
  __shared__ float ts[NR_][3];
  __shared__ float msk[NR_];
  int tid = threadIdx.x, bid = blockIdx.x;
  int qt = bid & 31, bh = bid >> 5;
  int b = bh >> 3, h = bh & 7;
  const unsigned int* kbase = kr + ((size_t)((h << 10) + (b << 9))) * 8;
  const unsigned int* vbase = vr + ((size_t)((h << 10) + (b << 9))) * 8;
  for (int idx = tid; idx < NR_ * 8; idx += 512) {
    int r = idx >> 3, u = idx & 7;
    ks[r][u] = kbase[idx];
    vs[r][u] = vbase[idx];
  }
  for (int idx = tid; idx < NR_; idx += 512) {
    int gr = (b << 9) + idx;
    ts[idx][0] = curT_r[gr * 3 + 0];
    ts[idx][1] = curT_r[gr * 3 + 1];
    ts[idx][2] = curT_r[gr * 3 + 2];
    msk[idx] = res_mask[gr];
  }
  __syncthreads();
  float c0 = weff[l * 32 + h], c1 = weff[l * 32 + 8 + h];
  float c2 = weff[l * 32 + 16 + h], c3 = weff[l * 32 + 24 + h];
  float be = beff[l * 8 + h];
  int w = tid >> 6, lane = tid & 63;

  for (int qi = 0; qi < 2; qi++) {
    int i = qt * 16 + w * 2 + qi;
    const unsigned int* qrow = qbU + ((size_t)((b << 9) + i)) * 64 + h * 8;
    uint4 qa = *(const uint4*)qrow;
    uint4 qc = *(const uint4*)(qrow + 4);
    half2_t qh[8];
    qh[0] = u2h(qa.x); qh[1] = u2h(qa.y); qh[2] = u2h(qa.z); qh[3] = u2h(qa.w);
    qh[4] = u2h(qc.x); qh[5] = u2h(qc.y); qh[6] = u2h(qc.z); qh[7] = u2h(qc.w);
    float tix = ts[i][0], tiy = ts[i][1], tiz = ts[i][2];
    float lsum = 0.f;
    float oacc[16];
#pragma unroll
    for (int d = 0; d < 16; d++) oacc[d] = 0.f;
#pragma unroll
    for (int jj = 0; jj < 8; jj++) {
      int j = lane + 64 * jj;
      float dot = 0.f;
#pragma unroll
      for (int u = 0; u < 8; u++) dot = FDOT2(qh[u], u2h(ks[j][u]), dot);
      float rx = tix - ts[j][0], ry = tiy - ts[j][1], rz = tiz - ts[j][2];
      float dist = sqrtf(rx * rx + ry * ry + rz * rz);
      float L = dot * 0.25f + c0 * rx + c1 * ry + c2 * rz + c3 * dist + be;
      if (msk[j] <= 0.f) L = -1e9f;
      float p = __expf(L);  // shift-free: logits bounded, softmax shift-invariant
      lsum += p;
#pragma unroll
      for (int u = 0; u < 8; u++) {
        half2_t vv = u2h(vs[j][u]);
        oacc[2 * u] += p * (float)vv.x;
        oacc[2 * u + 1] += p * (float)vv.y;
      }
    }
#pragma unroll
    for (int m = 1; m < 64; m <<= 1) {
      lsum += __shfl_xor(lsum, m, 64);
#pragma unroll
      for (int d = 0; d < 16; d++) oacc[d] += __shfl_xor(oacc[d], m, 64);
    }
    if (lane == 0) {
      float inv = 1.f / lsum;
      float* orow = ob + ((size_t)((b << 9) + i)) * D_ + h * DH_;
#pragma unroll
      for (int g = 0; g < 4; g++) {
        float4 o4 = make_float4(oacc[4 * g] * inv, oacc[4 * g + 1] * inv,
                                oacc[4 * g + 2] * inv, oacc[4 * g + 3] * inv);
        *(float4*)(orow + 4 * g) = o4;
      }
    }
  }
}

// ============ oproj + residual + {qkv(l+1) | head+frame [+qkv0]} ; 1 row/block ============
__global__ __launch_bounds__(256) void k_oproj(
    const float* __restrict__ ob, const unsigned int* __restrict__ woh,
    const float* __restrict__ bo, const unsigned int* __restrict__ qkvh,
    const float* __restrict__ featsIn, float* __restrict__ featsW,
    const float* __restrict__ featsL, unsigned int* __restrict__ qbU,
    unsigned int* __restrict__ kw, unsigned int* __restrict__ vw,
    const float* __restrict__ curT_r, float* __restrict__ curT_w, float* __restrict__ curR,
    const float* __restrict__ res_mask, const float* __restrict__ head_W,
    const float* __restrict__ head_b, int l, int lastLayer, int doQ0) {
  __shared__ float part[4][128];
  __shared__ float xsf[128];
  __shared__ unsigned int xh[64];
  int row = blockIdx.x;
  int tid = threadIdx.x;
  int w = tid >> 6, cp = tid & 63;
  if (tid < 64) xh[tid] = pack_h(ob[row * D_ + 2 * tid], ob[row * D_ + 2 * tid + 1]);
  __syncthreads();
  {
    const unsigned int* W = woh + (size_t)(l * 64) * 128;
    float a0 = 0.f, a1 = 0.f;
#pragma unroll
    for (int kk = 0; kk < 16; kk++) {
      int k = w * 16 + kk;
      uint2 ww = *(const uint2*)(W + k * 128 + 2 * cp);
      half2_t x = u2h(xh[k]);
      a0 = FDOT2(x, u2h(ww.x), a0);
      a1 = FDOT2(x, u2h(ww.y), a1);
    }
    *(float2*)&part[w][2 * cp] = make_float2(a0, a1);
  }
  __syncthreads();
  if (tid < 128) {
    float f = part[0][tid] + part[1][tid] + part[2][tid] + part[3][tid] + bo[l * D_ + tid] +
              featsIn[row * D_ + tid];
    featsW[row * D_ + tid] = f;
    xsf[tid] = f;
  }
  __syncthreads();
  if (tid < 64) xh[tid] = pack_h(xsf[2 * tid], xsf[2 * tid + 1]);
  __syncthreads();
  if (!lastLayer) {
    if (w < 3) {
      const unsigned int* Wm = qkvh + (size_t)((l + 1) * 3 + w) * 8192;
      float b0 = 0.f, b1 = 0.f;
#pragma unroll 16
      for (int kk = 0; kk < 64; kk++) {
        uint2 ww = *(const uint2*)(Wm + kk * 128 + 2 * cp);
        half2_t x = u2h(xh[kk]);
        b0 = FDOT2(x, u2h(ww.x), b0);
        b1 = FDOT2(x, u2h(ww.y), b1);
      }
      unsigned int pk = pack_h(b0, b1);
      int h = cp >> 3, u = cp & 7;
      if (w == 0) qbU[row * 64 + cp] = pk;
      else if (w == 1) kw[((h << 10) + row) * 8 + u] = pk;
      else vw[((h << 10) + row) * 8 + u] = pk;
    }
  } else {
    if (w == 0) {
      float f0 = xsf[2 * cp], f1 = xsf[2 * cp + 1];
      float pc[6];
#pragma unroll
      for (int c = 0; c < 6; c++)
        pc[c] = f0 * head_W[(2 * cp) * 6 + c] + f1 * head_W[(2 * cp + 1) * 6 + c];
#pragma unroll
      for (int m = 1; m < 64; m <<= 1)
#pragma unroll
        for (int c = 0; c < 6; c++) pc[c] += __shfl_xor(pc[c], m, 64);
      if (cp == 0) {
        float u[6];
#pragma unroll
        for (int c = 0; c < 6; c++) u[c] = pc[c] + head_b[c];
        float vx = u[0], vy = u[1], vz = u[2];
        float inv = rsqrtf(1.f + vx * vx + vy * vy + vz * vz);
        float qw = inv, qx = vx * inv, qy = vy * inv, qz = vz * inv;
        float Rd[9];
        Rd[0] = 1.f - 2.f * (qy * qy + qz * qz); Rd[1] = 2.f * (qx * qy - qw * qz);
        Rd[2] = 2.f * (qx * qz + qw * qy); Rd[3] = 2.f * (qx * qy + qw * qz);
        Rd[4] = 1.f - 2.f * (qx * qx + qz * qz); Rd[5] = 2.f * (qy * qz - qw * qx);
        Rd[6] = 2.f * (qx * qz - qw * qy); Rd[7] = 2.f * (qy * qz + qw * qx);
        Rd[8] = 1.f - 2.f * (qx * qx + qy * qy);
        float Ro[9];
#pragma unroll
        for (int c = 0; c < 9; c++) Ro[c] = curR[row * 9 + c];
        float Rn[9];
#pragma unroll
        for (int i2 = 0; i2 < 3; i2++)
#pragma unroll
          for (int kk = 0; kk < 3; kk++)
            Rn[i2 * 3 + kk] = Rd[i2 * 3 + 0] * Ro[0 * 3 + kk] +
                              Rd[i2 * 3 + 1] * Ro[1 * 3 + kk] +
                              Rd[i2 * 3 + 2] * Ro[2 * 3 + kk];
        float tx = curT_r[row * 3 + 0], ty = curT_r[row * 3 + 1], tz = curT_r[row * 3 + 2];
        float ux = u[3], uy = u[4], uz = u[5];
        float m = res_mask[row];
#pragma unroll
        for (int c = 0; c < 9; c++) curR[row * 9 + c] = Rn[c];
        curT_w[row * 3 + 0] = (tx + Rn[0] * ux + Rn[1] * uy + Rn[2] * uz) * m;
        curT_w[row * 3 + 1] = (ty + Rn[3] * ux + Rn[4] * uy + Rn[5] * uz) * m;
        curT_w[row * 3 + 2] = (tz + Rn[6] * ux + Rn[7] * uy + Rn[8] * uz) * m;
      }
    }
    if (doQ0) {
      __syncthreads();
      if (tid < 64)
        xh[tid] = pack_h(featsL[row * D_ + 2 * tid], featsL[row * D_ + 2 * tid + 1]);
      __syncthreads();
      if (w < 3) {
        const unsigned int* Wm = qkvh + (size_t)(0 * 3 + w) * 8192;
        float b0 = 0.f, b1 = 0.f;
#pragma unroll 16
        for (int kk = 0; kk < 64; kk++) {
          uint2 ww = *(const uint2*)(Wm + kk * 128 + 2 * cp);
          half2_t x = u2h(xh[kk]);
          b0 = FDOT2(x, u2h(ww.x), b0);
          b1 = FDOT2(x, u2h(ww.y), b1);
        }
        unsigned int pk = pack_h(b0, b1);
        int h = cp >> 3, u = cp & 7;
        if (w == 0) qbU[row * 64 + cp] = pk;
        else if (w == 1) kw[((h << 10) + row) * 8 + u] = pk;
        else vw[((h << 10) + row) * 8 + u] = pk;
      }
    }
  }
}

// ============ final frame composition + output ============
__global__ void k_final(const float* __restrict__ coords, const int* __restrict__ res_map,
                        const float* __restrict__ rots_bad, const float* __restrict__ trans_bad,
                        const float* __restrict__ curR, const float* __restrict__ curT,
                        float* __restrict__ out) {
  int a = blockIdx.x * blockDim.x + threadIdx.x;
  if (a < B_ * NR_) {
#pragma unroll
    for (int c = 0; c < 9; c++) out[a * 9 + c] = curR[a * 9 + c];
    out[B_ * NR_ * 9 + a * 3 + 0] = curT[a * 3 + 0];
    out[B_ * NR_ * 9 + a * 3 + 1] = curT[a * 3 + 1];
    out[B_ * NR_ * 9 + a * 3 + 2] = curT[a * 3 + 2];
  }
  if (a >= B_ * NA_) return;
  int b = a / NA_;
  int r = b * NR_ + res_map[a];
  float x0 = coords[a * 3 + 0], x1 = coords[a * 3 + 1], x2 = coords[a * 3 + 2];
  float R0[9], Rc[9];
#pragma unroll
  for (int c = 0; c < 9; c++) { R0[c] = rots_bad[r * 9 + c]; Rc[c] = curR[r * 9 + c]; }
  float t0x = trans_bad[r * 3 + 0], t0y = trans_bad[r * 3 + 1], t0z = trans_bad[r * 3 + 2];
  float dx = x0 - t0x, dy = x1 - t0y, dz = x2 - t0z;
  float lx = R0[0] * dx + R0[3] * dy + R0[6] * dz;
  float ly = R0[1] * dx + R0[4] * dy + R0[7] * dz;
  float lz = R0[2] * dx + R0[5] * dy + R0[8] * dz;
  float tcx = curT[r * 3 + 0], tcy = curT[r * 3 + 1], tcz = curT[r * 3 + 2];
  float fx = Rc[0] * lx + Rc[3] * ly + Rc[6] * lz + tcx;
  float fy = Rc[1] * lx + Rc[4] * ly + Rc[7] * lz + tcy;
  float fz = Rc[2] * lx + Rc[5] * ly + Rc[8] * lz + tcz;
  int off = B_ * NR_ * 12;
  out[off + a * 3 + 0] = fx;
  out[off + a * 3 + 1] = fy;
  out[off + a * 3 + 2] = fz;
}

extern "C" void kernel_launch(void* const* d_in, const int* in_sizes, int n_in,
                              void* d_out, int out_size, void* d_ws, size_t ws_size,
                              hipStream_t stream) {
  const float* coords    = (const float*)d_in[0];
  const int*   atype     = (const int*)d_in[1];
  const int*   rtype     = (const int*)d_in[2];
  // d_in[3] = mask (unused)
  const float* res_mask  = (const float*)d_in[4];
  const int*   res_map   = (const int*)d_in[5];
  const float* rots_bad  = (const float*)d_in[6];
  const float* trans_bad = (const float*)d_in[7];
  const float* atom_emb  = (const float*)d_in[8];
  const float* res_emb   = (const float*)d_in[9];
  const float* coord_W   = (const float*)d_in[10];
  const float* coord_b   = (const float*)d_in[11];
  const float* local_W   = (const float*)d_in[12];
  const float* local_b   = (const float*)d_in[13];
  const float* pair_W    = (const float*)d_in[14];
  const float* pair_b    = (const float*)d_in[15];
  const float* Wq        = (const float*)d_in[16];
  const float* Wk        = (const float*)d_in[17];
  const float* Wv        = (const float*)d_in[18];
  const float* Wb        = (const float*)d_in[19];
  const float* Wo        = (const float*)d_in[20];
  const float* bo        = (const float*)d_in[21];
  const float* head_W    = (const float*)d_in[22];
  const float* head_b    = (const float*)d_in[23];

  float* ws = (float*)d_ws;
  float* ob     = ws;  ws += 131072;   // aliased: feats0 (setup/localA), then attn out
  float* feats0 = ob;
  float* featsL = ws;  ws += 131072;
  float* featsW = ws;  ws += 131072;
  float* weff   = ws;  ws += 128;
  float* beff   = ws;  ws += 32;
  float* curR   = ws;  ws += 9216;
  float* curT0  = ws;  ws += 3072;
  float* curT1  = ws;  ws += 3072;
  unsigned int* wu = (unsigned int*)ws;
  unsigned int* qbU = wu;  wu += 65536;
  unsigned int* kbA = wu;  wu += 65536;
  unsigned int* vbA = wu;  wu += 65536;
  unsigned int* kbB = wu;  wu += 65536;
  unsigned int* vbB = wu;  wu += 65536;
  unsigned int* lwh  = wu; wu += 40960;
  unsigned int* qkvh = wu; wu += 98304;
  unsigned int* woh  = wu; wu += 32768;
  float* out = (float*)d_out;

  k_setup<<<256, 256, 0, stream>>>(coords, atype, rtype, res_map, rots_bad, trans_bad,
                                   atom_emb, res_emb, coord_W, coord_b, local_W, pair_W,
                                   pair_b, Wq, Wk, Wv, Wb, Wo, feats0, weff, beff, curR,
                                   curT0, lwh, qkvh, woh);
  k_localA<<<1024, 256, 0, stream>>>(feats0, lwh, local_b, qkvh, featsL, qbU, kbA, vbA);

  for (int iter = 0; iter < NITER_; iter++) {
    float* Tr = (iter & 1) ? curT1 : curT0;
    float* Tw = (iter & 1) ? curT0 : curT1;
    for (int l = 0; l < NIPA_; l++) {
      unsigned int* krd = (l & 1) ? kbB : kbA;
      unsigned int* vrd = (l & 1) ? vbB : vbA;
      unsigned int* kwr = (l & 1) ? kbA : kbB;
      unsigned int* vwr = (l & 1) ? vbA : vbB;
      k_attn<<<512, 512, 0, stream>>>(qbU, krd, vrd, Tr, res_mask, weff, beff, ob, l);
      k_oproj<<<1024, 256, 0, stream>>>(ob, woh, bo, qkvh, (l == 0) ? featsL : featsW,
                                        featsW, featsL, qbU, kwr, vwr, Tr, Tw, curR,
                                        res_mask, head_W, head_b, l,
                                        (l == NIPA_ - 1) ? 1 : 0,
                                        (l == NIPA_ - 1 && iter < NITER_ - 1) ? 1 : 0);
    }
  }
  k_final<<<(B_ * NA_ + 255) / 256, 256, 0, stream>>>(coords, res_map, rots_bad, trans_bad,
                                                      curR, curT1, out);
}

// Round 8
// 294.804 us; speedup vs baseline: 6.4241x; 1.3966x over previous
//
#include <hip/hip_runtime.h>
#include <math.h>

#define B_ 2
#define NA_ 4096
#define NR_ 512
#define D_ 128
#define H_ 8
#define DH_ 16
#define NLOCAL_ 5
#define NIPA_ 4
#define NITER_ 3

typedef _Float16 half2_t __attribute__((ext_vector_type(2)));
typedef _Float16 f16x4 __attribute__((ext_vector_type(4)));
typedef float f32x4 __attribute__((ext_vector_type(4)));

#if __has_builtin(__builtin_amdgcn_fdot2)
#define FDOT2(a, b, c) __builtin_amdgcn_fdot2((a), (b), (c), false)
#else
__device__ __forceinline__ float FDOT2(half2_t a, half2_t b, float c) {
  return c + (float)a.x * (float)b.x + (float)a.y * (float)b.y;
}
#endif

#define MFMA16(a, b, c) __builtin_amdgcn_mfma_f32_16x16x16f16((a), (b), (c), 0, 0, 0)

__device__ __forceinline__ unsigned int pack_h(float a, float b) {
  union { unsigned int u; half2_t h; } x;
  x.h = half2_t{(_Float16)a, (_Float16)b};
  return x.u;
}
__device__ __forceinline__ half2_t u2h(unsigned int u) {
  union { unsigned int u; half2_t h; } x;
  x.u = u;
  return x.h;
}
__device__ __forceinline__ f16x4 mk4(unsigned int a, unsigned int b) {
  union { uint2 u; f16x4 h; } x;
  x.u = make_uint2(a, b);
  return x.h;
}
__device__ __forceinline__ float gelu_tanh(float x) {
  float x3 = x * x * x;
  return 0.5f * x * (1.0f + tanhf(0.7978845608028654f * (x + 0.044715f * x3)));
}

// ============ setup: weight pack (f16 k-pair-major) + weff + pooling + frame init ========
__global__ __launch_bounds__(256) void k_setup(
    const float* __restrict__ coords, const int* __restrict__ atype,
    const int* __restrict__ rtype, const int* __restrict__ res_map,
    const float* __restrict__ rots_bad, const float* __restrict__ trans_bad,
    const float* __restrict__ atom_emb, const float* __restrict__ res_emb,
    const float* __restrict__ coord_W, const float* __restrict__ coord_b,
    const float* __restrict__ local_W, const float* __restrict__ pair_W,
    const float* __restrict__ pair_b, const float* __restrict__ Wq,
    const float* __restrict__ Wk, const float* __restrict__ Wv, const float* __restrict__ Wb,
    const float* __restrict__ Wo, float* __restrict__ feats0, float* __restrict__ weff,
    float* __restrict__ beff, float* __restrict__ curR, float* __restrict__ curT0,
    unsigned int* __restrict__ lwh, unsigned int* __restrict__ qkvh,
    unsigned int* __restrict__ woh) {
  int tid = threadIdx.x, bid = blockIdx.x;
  int gtid = (bid << 8) + tid;
  // layouts: lwh[l][kk][c] = half2(W[2kk][c], W[2kk+1][c]) etc. (kk = k-pair, c = col)
  for (int t = gtid; t < 172032; t += 65536) {
    if (t < 40960) {
      int c = t & 127, kk = (t >> 7) & 63, l = t >> 13;
      const float* s = local_W + (size_t)l * 16384 + (2 * kk) * 128 + c;
      lwh[t] = pack_h(s[0], s[128]);
    } else if (t < 139264) {
      int t2 = t - 40960;
      int c = t2 & 127, kk = (t2 >> 7) & 63, lm = t2 >> 13;
      int l = lm / 3, m = lm % 3;
      const float* base = (m == 0) ? Wq : ((m == 1) ? Wk : Wv);
      const float* s = base + (size_t)l * 16384 + (2 * kk) * 128 + c;
      qkvh[t2] = pack_h(s[0], s[128]);
    } else {
      int t3 = t - 139264;
      int c = t3 & 127, kk = (t3 >> 7) & 63, l = t3 >> 13;
      const float* s = Wo + (size_t)l * 16384 + (2 * kk) * 128 + c;
      woh[t3] = pack_h(s[0], s[128]);
    }
  }
  if (gtid < 160) {
    int l = gtid / 40, rest = gtid % 40;
    int c = rest / 8, h = rest & 7;
    const float* row = (c < 4) ? (pair_W + c * D_) : pair_b;
    float acc = 0.f;
    for (int d = 0; d < D_; d++) acc += row[d] * Wb[l * D_ * H_ + d * H_ + h];
    if (c < 4) weff[l * 32 + c * 8 + h] = acc;
    else beff[l * 8 + h] = acc;
  }
  if (gtid < 9216) curR[gtid] = rots_bad[gtid];
  else if (gtid < 12288) curT0[gtid - 9216] = trans_bad[gtid - 9216];
  for (int rp = 0; rp < 2; rp++) {
    int row = (bid << 2) + (rp << 1) + (tid >> 7);
    int d = tid & 127;
    int b = row >> 9, rr = row & (NR_ - 1);
    const int* rm = res_map + b * NA_;
    int lo = 0, hi = NA_;
    while (lo < hi) { int mid = (lo + hi) >> 1; if (rm[mid] < rr) lo = mid + 1; else hi = mid; }
    int start = lo;
    hi = NA_;
    while (lo < hi) { int mid = (lo + hi) >> 1; if (rm[mid] < rr + 1) lo = mid + 1; else hi = mid; }
    int end = lo;
    float w0 = coord_W[d], w1 = coord_W[D_ + d], w2 = coord_W[2 * D_ + d], cb = coord_b[d];
    float s = 0.f;
    for (int a = start; a < end; a++) {
      int ga = b * NA_ + a;
      s += atom_emb[atype[ga] * D_ + d] + res_emb[rtype[ga] * D_ + d] +
           coords[ga * 3 + 0] * w0 + coords[ga * 3 + 1] * w1 + coords[ga * 3 + 2] * w2 + cb;
    }
    feats0[row * D_ + d] = s / ((float)(end - start) + 1e-8f);
  }
}

// ============ localA: 5-layer MLP + layer-0 QKV ; 4 rows/block (wave = row) ============
__global__ __launch_bounds__(256) void k_localA(
    const float* __restrict__ feats0, const unsigned int* __restrict__ lwh,
    const float* __restrict__ local_b, const unsigned int* __restrict__ qkvh,
    float* __restrict__ featsL, unsigned int* __restrict__ qbU,
    unsigned int* __restrict__ kw, unsigned int* __restrict__ vw) {
  __shared__ unsigned int xh[4][64];
  __shared__ float xsf[4][128];
  int tid = threadIdx.x;
  int w = tid >> 6, cp = tid & 63;
  int row0 = blockIdx.x << 2;
  int row = row0 + w;
  float2 x2 = *(const float2*)(feats0 + (size_t)row * D_ + 2 * cp);
  float y0 = x2.x, y1 = x2.y;
  xsf[w][2 * cp] = y0; xsf[w][2 * cp + 1] = y1;
  xh[w][cp] = pack_h(y0, y1);
  for (int l = 0; l < NLOCAL_; l++) {
    const unsigned int* W = lwh + l * 8192;
    float a0 = 0.f, a1 = 0.f;
#pragma unroll 8
    for (int kk = 0; kk < 64; kk++) {
      uint2 ww = *(const uint2*)(W + kk * 128 + 2 * cp);
      half2_t x = u2h(xh[w][kk]);
      a0 = FDOT2(x, u2h(ww.x), a0);
      a1 = FDOT2(x, u2h(ww.y), a1);
    }
    y0 = gelu_tanh(a0 + local_b[l * D_ + 2 * cp]) + xsf[w][2 * cp];
    y1 = gelu_tanh(a1 + local_b[l * D_ + 2 * cp + 1]) + xsf[w][2 * cp + 1];
    xsf[w][2 * cp] = y0; xsf[w][2 * cp + 1] = y1;  // wave-lockstep safe
    xh[w][cp] = pack_h(y0, y1);
  }
  *(float2*)(featsL + (size_t)row * D_ + 2 * cp) = make_float2(y0, y1);
  __syncthreads();
  if (w < 3) {
    const unsigned int* Wm = qkvh + (size_t)w * 8192;  // layer 0
    float bacc[4][2] = {};
#pragma unroll 8
    for (int kk = 0; kk < 64; kk++) {
      uint2 ww = *(const uint2*)(Wm + kk * 128 + 2 * cp);
#pragma unroll
      for (int r = 0; r < 4; r++) {
        half2_t x = u2h(xh[r][kk]);
        bacc[r][0] = FDOT2(x, u2h(ww.x), bacc[r][0]);
        bacc[r][1] = FDOT2(x, u2h(ww.y), bacc[r][1]);
      }
    }
    int h = cp >> 3, u = cp & 7;
#pragma unroll
    for (int r = 0; r < 4; r++) {
      unsigned int pk = pack_h(bacc[r][0], bacc[r][1]);
      int rr = row0 + r;
      if (w == 0) qbU[rr * 64 + cp] = pk;
      else if (w == 1) kw[((h << 10) + rr) * 8 + u] = pk;
      else vw[((h << 10) + rr) * 8 + u] = pk;
    }
  }
}

// ============ MFMA attention: block=(bh,g), 2 waves, 1 q-tile(16q) per wave ============
__global__ __launch_bounds__(128) void k_attn(
    const unsigned int* __restrict__ qbU, const unsigned int* __restrict__ kr,
    const unsigned int* __restrict__ vr, const float* __restrict__ curT_r,
    const float* __restrict__ res_mask, const float* __restrict__ weff,
    const float* __restrict__ beff, float* __restrict__ ob, int l) {
  __shared__ unsigned int ks[NR_][9];   // K row-major f16 pairs, pad 9 (conflict-free)
  __shared__ unsigned int vt[16][257];  // V^T: vt[d][jj] = halves (V[2jj][d], V[2jj+1][d])
  __shared__ float4 ts4[NR_];           // xyz = curT, w = mask
  int tid = threadIdx.x, bid = blockIdx.x;
  int g = bid & 15, bh = bid >> 4;
  int b = bh >> 3, h = bh & 7;
  const unsigned int* kbase = kr + ((size_t)((h << 10) + (b << 9))) * 8;
  const unsigned int* vbase = vr + ((size_t)((h << 10) + (b << 9))) * 8;
#pragma unroll 4
  for (int idx = tid; idx < NR_ * 8; idx += 128) ks[idx >> 3][idx & 7] = kbase[idx];
#pragma unroll 4
  for (int idx = tid; idx < NR_ * 4; idx += 128) {
    int rp = idx >> 3, u = idx & 7;
    unsigned int a = vbase[(2 * rp) * 8 + u];
    unsigned int c = vbase[(2 * rp + 1) * 8 + u];
    vt[2 * u][rp] = (a & 0xffffu) | (c << 16);
    vt[2 * u + 1][rp] = (a >> 16) | (c & 0xffff0000u);
  }
#pragma unroll 2
  for (int idx = tid; idx < NR_; idx += 128) {
    int gr = (b << 9) + idx;
    ts4[idx] = make_float4(curT_r[gr * 3 + 0], curT_r[gr * 3 + 1], curT_r[gr * 3 + 2],
                           res_mask[gr]);
  }
  __syncthreads();
  int w = tid >> 6, lane = tid & 63;
  int qt = g * 2 + w;                 // q-tile 0..31
  int lrow = lane & 15, lgrp = lane >> 4;
  int qrow = (b << 9) + qt * 16 + lrow;
  // Q^T B-frag: lane holds Q[qt*16+lrow][4*lgrp .. +3]
  const uint2 qp = *(const uint2*)(qbU + (size_t)qrow * 64 + h * 8 + lgrp * 2);
  f16x4 qf = mk4(qp.x, qp.y);
  float4 ti = ts4[qt * 16 + lrow];
  float c0 = weff[l * 32 + h], c1 = weff[l * 32 + 8 + h];
  float c2 = weff[l * 32 + 16 + h], c3 = weff[l * 32 + 24 + h];
  float be = beff[l * 8 + h];
  f32x4 zero = {0.f, 0.f, 0.f, 0.f};
  f32x4 oacc = zero;
  float lsum = 0.f;
  for (int jt = 0; jt < 32; jt++) {
    int jr = jt * 16 + lrow;
    // K A-frag: lane holds K[jt*16+lrow][4*lgrp .. +3]
    f16x4 kf = mk4(ks[jr][lgrp * 2], ks[jr][lgrp * 2 + 1]);
    // S^T tile: lane holds S[q = lrow][j = jt*16 + 4*lgrp + reg]
    f32x4 s = MFMA16(kf, qf, zero);
    f16x4 pv;
#pragma unroll
    for (int r = 0; r < 4; r++) {
      int jg = jt * 16 + lgrp * 4 + r;
      float4 tj = ts4[jg];  // broadcast across 16-lane group
      float rx = ti.x - tj.x, ry = ti.y - tj.y, rz = ti.z - tj.z;
      float dist = sqrtf(rx * rx + ry * ry + rz * rz);
      float L = s[r] * 0.25f + c0 * rx + c1 * ry + c2 * rz + c3 * dist + be;
      L = (tj.w > 0.f) ? L : -1e9f;
      float p = __expf(L);  // shift-free: logits bounded, softmax shift-invariant
      lsum += p;
      pv[r] = (_Float16)p;
    }
    // V^T A-frag: lane holds V^T[lrow][jt*16 + 4*lgrp .. +3]
    f16x4 vf = mk4(vt[lrow][jt * 8 + lgrp * 2], vt[lrow][jt * 8 + lgrp * 2 + 1]);
    // O^T += V^T · P^T  (P^T frag == S^T D-frag layout: no data movement)
    oacc = MFMA16(vf, pv, oacc);
  }
  lsum += __shfl_xor(lsum, 16, 64);
  lsum += __shfl_xor(lsum, 32, 64);
  float inv = 1.f / lsum;
  // O^T frag: lane holds O[q = lrow][d = 4*lgrp + reg]
  float4 o4 = make_float4(oacc[0] * inv, oacc[1] * inv, oacc[2] * inv, oacc[3] * inv);
  *(float4*)(ob + (size_t)qrow * D_ + h * DH_ + lgrp * 4) = o4;
}

// ============ oproj + residual + {qkv(l+1) | head+frame [+qkv0]} ; 4 rows/block ============
__global__ __launch_bounds__(256) void k_oproj(
    const float* __restrict__ ob, const unsigned int* __restrict__ woh,
    const float* __restrict__ bo, const unsigned int* __restrict__ qkvh,
    const float* __restrict__ featsIn, float* __restrict__ featsW,
    const float* __restrict__ featsL, unsigned int* __restrict__ qbU,
    unsigned int* __restrict__ kw, unsigned int* __restrict__ vw,
    const float* __restrict__ curT_r, float* __restrict__ curT_w, float* __restrict__ curR,
    const float* __restrict__ res_mask, const float* __restrict__ head_W,
    const float* __restrict__ head_b, int l, int lastLayer, int doQ0) {
  __shared__ float part[4][4][128];
  __shared__ float xsf[4][128];
  __shared__ unsigned int xh[4][64];
  int tid = threadIdx.x;
  int w = tid >> 6, cp = tid & 63;
  int row0 = blockIdx.x << 2;
  {
    float2 o2 = *(const float2*)(ob + (size_t)(row0 + w) * D_ + 2 * cp);
    xh[w][cp] = pack_h(o2.x, o2.y);
  }
  __syncthreads();
  // phase 1: oproj, k-split across waves, all 4 rows per wave
  {
    const unsigned int* W = woh + (size_t)l * 8192 + (w * 16) * 128;
    float a[4][2] = {};
#pragma unroll
    for (int kk = 0; kk < 16; kk++) {
      uint2 ww = *(const uint2*)(W + kk * 128 + 2 * cp);
#pragma unroll
      for (int r = 0; r < 4; r++) {
        half2_t x = u2h(xh[r][w * 16 + kk]);
        a[r][0] = FDOT2(x, u2h(ww.x), a[r][0]);
        a[r][1] = FDOT2(x, u2h(ww.y), a[r][1]);
      }
    }
#pragma unroll
    for (int r = 0; r < 4; r++) {
      part[w][r][2 * cp] = a[r][0];
      part[w][r][2 * cp + 1] = a[r][1];
    }
  }
  __syncthreads();
  for (int t = tid; t < 512; t += 256) {
    int r = t >> 7, c = t & 127;
    float f = part[0][r][c] + part[1][r][c] + part[2][r][c] + part[3][r][c] +
              bo[l * D_ + c] + featsIn[(size_t)(row0 + r) * D_ + c];
    featsW[(size_t)(row0 + r) * D_ + c] = f;
    xsf[r][c] = f;
  }
  __syncthreads();
  xh[w][cp] = pack_h(xsf[w][2 * cp], xsf[w][2 * cp + 1]);
  __syncthreads();
  if (!lastLayer) {
    if (w < 3) {
      const unsigned int* Wm = qkvh + (size_t)((l + 1) * 3 + w) * 8192;
      float bacc[4][2] = {};
#pragma unroll 8
      for (int kk = 0; kk < 64; kk++) {
        uint2 ww = *(const uint2*)(Wm + kk * 128 + 2 * cp);
#pragma unroll
        for (int r = 0; r < 4; r++) {
          half2_t x = u2h(xh[r][kk]);
          bacc[r][0] = FDOT2(x, u2h(ww.x), bacc[r][0]);
          bacc[r][1] = FDOT2(x, u2h(ww.y), bacc[r][1]);
        }
      }
      int h = cp >> 3, u = cp & 7;
#pragma unroll
      for (int r = 0; r < 4; r++) {
        unsigned int pk = pack_h(bacc[r][0], bacc[r][1]);
        int rr = row0 + r;
        if (w == 0) qbU[rr * 64 + cp] = pk;
        else if (w == 1) kw[((h << 10) + rr) * 8 + u] = pk;
        else vw[((h << 10) + rr) * 8 + u] = pk;
      }
    }
  } else {
    // head + frame update: wave w handles row row0+w
    int row = row0 + w;
    float f0 = xsf[w][2 * cp], f1 = xsf[w][2 * cp + 1];
    float pc[6];
#pragma unroll
    for (int c = 0; c < 6; c++)
      pc[c] = f0 * head_W[(2 * cp) * 6 + c] + f1 * head_W[(2 * cp + 1) * 6 + c];
#pragma unroll
    for (int m = 1; m < 64; m <<= 1)
#pragma unroll
      for (int c = 0; c < 6; c++) pc[c] += __shfl_xor(pc[c], m, 64);
    if (cp == 0) {
      float u[6];
#pragma unroll
      for (int c = 0; c < 6; c++) u[c] = pc[c] + head_b[c];
      float vx = u[0], vy = u[1], vz = u[2];
      float inv = rsqrtf(1.f + vx * vx + vy * vy + vz * vz);
      float qw = inv, qx = vx * inv, qy = vy * inv, qz = vz * inv;
      float Rd[9];
      Rd[0] = 1.f - 2.f * (qy * qy + qz * qz); Rd[1] = 2.f * (qx * qy - qw * qz);
      Rd[2] = 2.f * (qx * qz + qw * qy); Rd[3] = 2.f * (qx * qy + qw * qz);
      Rd[4] = 1.f - 2.f * (qx * qx + qz * qz); Rd[5] = 2.f * (qy * qz - qw * qx);
      Rd[6] = 2.f * (qx * qz - qw * qy); Rd[7] = 2.f * (qy * qz + qw * qx);
      Rd[8] = 1.f - 2.f * (qx * qx + qy * qy);
      float Ro[9];
#pragma unroll
      for (int c = 0; c < 9; c++) Ro[c] = curR[row * 9 + c];
      float Rn[9];
#pragma unroll
      for (int i2 = 0; i2 < 3; i2++)
#pragma unroll
        for (int kk = 0; kk < 3; kk++)
          Rn[i2 * 3 + kk] = Rd[i2 * 3 + 0] * Ro[0 * 3 + kk] +
                            Rd[i2 * 3 + 1] * Ro[1 * 3 + kk] +
                            Rd[i2 * 3 + 2] * Ro[2 * 3 + kk];
      float tx = curT_r[row * 3 + 0], ty = curT_r[row * 3 + 1], tz = curT_r[row * 3 + 2];
      float ux = u[3], uy = u[4], uz = u[5];
      float m = res_mask[row];
#pragma unroll
      for (int c = 0; c < 9; c++) curR[row * 9 + c] = Rn[c];
      curT_w[row * 3 + 0] = (tx + Rn[0] * ux + Rn[1] * uy + Rn[2] * uz) * m;
      curT_w[row * 3 + 1] = (ty + Rn[3] * ux + Rn[4] * uy + Rn[5] * uz) * m;
      curT_w[row * 3 + 2] = (tz + Rn[6] * ux + Rn[7] * uy + Rn[8] * uz) * m;
    }
    if (doQ0) {
      float2 fl = *(const float2*)(featsL + (size_t)(row0 + w) * D_ + 2 * cp);
      xh[w][cp] = pack_h(fl.x, fl.y);
      __syncthreads();
      if (w < 3) {
        const unsigned int* Wm = qkvh + (size_t)w * 8192;  // layer 0
        float bacc[4][2] = {};
#pragma unroll 8
        for (int kk = 0; kk < 64; kk++) {
          uint2 ww = *(const uint2*)(Wm + kk * 128 + 2 * cp);
#pragma unroll
          for (int r = 0; r < 4; r++) {
            half2_t x = u2h(xh[r][kk]);
            bacc[r][0] = FDOT2(x, u2h(ww.x), bacc[r][0]);
            bacc[r][1] = FDOT2(x, u2h(ww.y), bacc[r][1]);
          }
        }
        int h = cp >> 3, u = cp & 7;
#pragma unroll
        for (int r = 0; r < 4; r++) {
          unsigned int pk = pack_h(bacc[r][0], bacc[r][1]);
          int rr = row0 + r;
          if (w == 0) qbU[rr * 64 + cp] = pk;
          else if (w == 1) kw[((h << 10) + rr) * 8 + u] = pk;
          else vw[((h << 10) + rr) * 8 + u] = pk;
        }
      }
    }
  }
}

// ============ final frame composition + output ============
__global__ void k_final(const float* __restrict__ coords, const int* __restrict__ res_map,
                        const float* __restrict__ rots_bad, const float* __restrict__ trans_bad,
                        const float* __restrict__ curR, const float* __restrict__ curT,
                        float* __restrict__ out) {
  int a = blockIdx.x * blockDim.x + threadIdx.x;
  if (a < B_ * NR_) {
#pragma unroll
    for (int c = 0; c < 9; c++) out[a * 9 + c] = curR[a * 9 + c];
    out[B_ * NR_ * 9 + a * 3 + 0] = curT[a * 3 + 0];
    out[B_ * NR_ * 9 + a * 3 + 1] = curT[a * 3 + 1];
    out[B_ * NR_ * 9 + a * 3 + 2] = curT[a * 3 + 2];
  }
  if (a >= B_ * NA_) return;
  int b = a / NA_;
  int r = b * NR_ + res_map[a];
  float x0 = coords[a * 3 + 0], x1 = coords[a * 3 + 1], x2 = coords[a * 3 + 2];
  float R0[9], Rc[9];
#pragma unroll
  for (int c = 0; c < 9; c++) { R0[c] = rots_bad[r * 9 + c]; Rc[c] = curR[r * 9 + c]; }
  float t0x = trans_bad[r * 3 + 0], t0y = trans_bad[r * 3 + 1], t0z = trans_bad[r * 3 + 2];
  float dx = x0 - t0x, dy = x1 - t0y, dz = x2 - t0z;
  float lx = R0[0] * dx + R0[3] * dy + R0[6] * dz;
  float ly = R0[1] * dx + R0[4] * dy + R0[7] * dz;
  float lz = R0[2] * dx + R0[5] * dy + R0[8] * dz;
  float tcx = curT[r * 3 + 0], tcy = curT[r * 3 + 1], tcz = curT[r * 3 + 2];
  float fx = Rc[0] * lx + Rc[3] * ly + Rc[6] * lz + tcx;
  float fy = Rc[1] * lx + Rc[4] * ly + Rc[7] * lz + tcy;
  float fz = Rc[2] * lx + Rc[5] * ly + Rc[8] * lz + tcz;
  int off = B_ * NR_ * 12;
  out[off + a * 3 + 0] = fx;
  out[off + a * 3 + 1] = fy;
  out[off + a * 3 + 2] = fz;
}

extern "C" void kernel_launch(void* const* d_in, const int* in_sizes, int n_in,
                              void* d_out, int out_size, void* d_ws, size_t ws_size,
                              hipStream_t stream) {
  const float* coords    = (const float*)d_in[0];
  const int*   atype     = (const int*)d_in[1];
  const int*   rtype     = (const int*)d_in[2];
  // d_in[3] = mask (unused)
  const float* res_mask  = (const float*)d_in[4];
  const int*   res_map   = (const int*)d_in[5];
  const float* rots_bad  = (const float*)d_in[6];
  const float* trans_bad = (const float*)d_in[7];
  const float* atom_emb  = (const float*)d_in[8];
  const float* res_emb   = (const float*)d_in[9];
  const float* coord_W   = (const float*)d_in[10];
  const float* coord_b   = (const float*)d_in[11];
  const float* local_W   = (const float*)d_in[12];
  const float* local_b   = (const float*)d_in[13];
  const float* pair_W    = (const float*)d_in[14];
  const float* pair_b    = (const float*)d_in[15];
  const float* Wq        = (const float*)d_in[16];
  const float* Wk        = (const float*)d_in[17];
  const float* Wv        = (const float*)d_in[18];
  const float* Wb        = (const float*)d_in[19];
  const float* Wo        = (const float*)d_in[20];
  const float* bo        = (const float*)d_in[21];
  const float* head_W    = (const float*)d_in[22];
  const float* head_b    = (const float*)d_in[23];

  float* ws = (float*)d_ws;
  float* ob     = ws;  ws += 131072;   // aliased: feats0 (setup/localA), then attn out
  float* feats0 = ob;
  float* featsL = ws;  ws += 131072;
  float* featsW = ws;  ws += 131072;
  float* weff   = ws;  ws += 128;
  float* beff   = ws;  ws += 32;
  float* curR   = ws;  ws += 9216;
  float* curT0  = ws;  ws += 3072;
  float* curT1  = ws;  ws += 3072;
  unsigned int* wu = (unsigned int*)ws;
  unsigned int* qbU = wu;  wu += 65536;
  unsigned int* kbA = wu;  wu += 65536;
  unsigned int* vbA = wu;  wu += 65536;
  unsigned int* kbB = wu;  wu += 65536;
  unsigned int* vbB = wu;  wu += 65536;
  unsigned int* lwh  = wu; wu += 40960;
  unsigned int* qkvh = wu; wu += 98304;
  unsigned int* woh  = wu; wu += 32768;
  float* out = (float*)d_out;

  k_setup<<<256, 256, 0, stream>>>(coords, atype, rtype, res_map, rots_bad, trans_bad,
                                   atom_emb, res_emb, coord_W, coord_b, local_W, pair_W,
                                   pair_b, Wq, Wk, Wv, Wb, Wo, feats0, weff, beff, curR,
                                   curT0, lwh, qkvh, woh);
  k_localA<<<256, 256, 0, stream>>>(feats0, lwh, local_b, qkvh, featsL, qbU, kbA, vbA);

  for (int iter = 0; iter < NITER_; iter++) {
    float* Tr = (iter & 1) ? curT1 : curT0;
    float* Tw = (iter & 1) ? curT0 : curT1;
    for (int l = 0; l < NIPA_; l++) {
      unsigned int* krd = (l & 1) ? kbB : kbA;
      unsigned int* vrd = (l & 1) ? vbB : vbA;
      unsigned int* kwr = (l & 1) ? kbA : kbB;
      unsigned int* vwr = (l & 1) ? vbA : vbB;
      k_attn<<<256, 128, 0, stream>>>(qbU, krd, vrd, Tr, res_mask, weff, beff, ob, l);
      k_oproj<<<256, 256, 0, stream>>>(ob, woh, bo, qkvh, (l == 0) ? featsL : featsW,
                                       featsW, featsL, qbU, kwr, vwr, Tr, Tw, curR,
                                       res_mask, head_W, head_b, l,
                                       (l == NIPA_ - 1) ? 1 : 0,
                                       (l == NIPA_ - 1 && iter < NITER_ - 1) ? 1 : 0);
    }
  }
  k_final<<<(B_ * NA_ + 255) / 256, 256, 0, stream>>>(coords, res_map, rots_bad, trans_bad,
                                                      curR, curT1, out);
}